// Round 1
// baseline (3495.552 us; speedup 1.0000x reference)
//
#include <hip/hip_runtime.h>

#define D 128

// ---------------- support = in @ W  (W is [128][128] row-major) --------------
// One wave (64 lanes) per row; lane l computes output cols l and l+64.
__global__ void gemm_rowwave(const float* __restrict__ in, const float* __restrict__ W,
                             float* __restrict__ out, int nrows) {
    int wave = (blockIdx.x * blockDim.x + threadIdx.x) >> 6;
    int lane = threadIdx.x & 63;
    if (wave >= nrows) return;
    const float* inr = in + (size_t)wave * D;
    float rv0 = inr[lane];
    float rv1 = inr[lane + 64];
    float acc0 = 0.f, acc1 = 0.f;
#pragma unroll 8
    for (int k = 0; k < 64; ++k) {
        float hk = __shfl(rv0, k);
        acc0 += hk * W[k * D + lane];
        acc1 += hk * W[k * D + lane + 64];
    }
#pragma unroll 8
    for (int k = 0; k < 64; ++k) {
        float hk = __shfl(rv1, k);
        acc0 += hk * W[(k + 64) * D + lane];
        acc1 += hk * W[(k + 64) * D + lane + 64];
    }
    out[(size_t)wave * D + lane] = acc0;
    out[(size_t)wave * D + lane + 64] = acc1;
}

// ---------------- zero a buffer ----------------------------------------------
__global__ void zero_f4(float4* __restrict__ p, int n4) {
    int i = blockIdx.x * blockDim.x + threadIdx.x;
    if (i < n4) p[i] = make_float4(0.f, 0.f, 0.f, 0.f);
}

// ---------------- scatter: agg[dst] += support[src] * w ----------------------
// 32 threads per edge, each handles 4 consecutive channels (float4 gather).
__global__ void scatter_edges(const float* __restrict__ sup, const int* __restrict__ src,
                              const int* __restrict__ dst, const float* __restrict__ w,
                              float* __restrict__ agg, int E) {
    long long idx = (long long)blockIdx.x * blockDim.x + threadIdx.x;
    int e = (int)(idx >> 5);
    if (e >= E) return;
    int d = ((int)idx & 31) << 2;
    int s = src[e];
    int t = dst[e];
    float wt = w[e];
    const float4 v = *reinterpret_cast<const float4*>(sup + (size_t)s * D + d);
    float* a = agg + (size_t)t * D + d;
    atomicAdd(a + 0, v.x * wt);
    atomicAdd(a + 1, v.y * wt);
    atomicAdd(a + 2, v.z * wt);
    atomicAdd(a + 3, v.w * wt);
}

// ---------------- in-place bias + relu ---------------------------------------
__global__ void bias_relu4(float4* __restrict__ a, const float* __restrict__ b, int n4) {
    int i = blockIdx.x * blockDim.x + threadIdx.x;
    if (i >= n4) return;
    float4 v = a[i];
    int c = (i << 2) & (D - 1);
    v.x = fmaxf(v.x + b[c + 0], 0.f);
    v.y = fmaxf(v.y + b[c + 1], 0.f);
    v.z = fmaxf(v.z + b[c + 2], 0.f);
    v.w = fmaxf(v.w + b[c + 3], 0.f);
    a[i] = v;
}

// ---------------- fused GRU gates --------------------------------------------
// One wave per row. Lane l accumulates gate columns {l, l+64, l+128, l+192,
// l+256, l+320} for both gate_x (from h) and gate_h (from hidden). With the
// 3-way split i_r|i_i|i_n, lane l then owns exactly output cols l and l+64.
__global__ void gru_gate(const float* __restrict__ h, const float* __restrict__ hidden,
                         const float* __restrict__ Wx, const float* __restrict__ bx,
                         const float* __restrict__ Wh, const float* __restrict__ bh,
                         float* __restrict__ out, int nrows) {
    int wave = (blockIdx.x * blockDim.x + threadIdx.x) >> 6;
    int lane = threadIdx.x & 63;
    if (wave >= nrows) return;
    const float* hr = h + (size_t)wave * D;
    const float* dr = hidden + (size_t)wave * D;
    float hv0 = hr[lane], hv1 = hr[lane + 64];
    float dv0 = dr[lane], dv1 = dr[lane + 64];
    float gx[6] = {0.f, 0.f, 0.f, 0.f, 0.f, 0.f};
    float gh[6] = {0.f, 0.f, 0.f, 0.f, 0.f, 0.f};
#pragma unroll 4
    for (int k = 0; k < 64; ++k) {
        float a = __shfl(hv0, k);
        float c = __shfl(dv0, k);
        const float* wxr = Wx + k * (3 * D) + lane;
        const float* whr = Wh + k * (3 * D) + lane;
#pragma unroll
        for (int j = 0; j < 6; ++j) {
            gx[j] += a * wxr[j * 64];
            gh[j] += c * whr[j * 64];
        }
    }
#pragma unroll 4
    for (int k = 0; k < 64; ++k) {
        float a = __shfl(hv1, k);
        float c = __shfl(dv1, k);
        const float* wxr = Wx + (k + 64) * (3 * D) + lane;
        const float* whr = Wh + (k + 64) * (3 * D) + lane;
#pragma unroll
        for (int j = 0; j < 6; ++j) {
            gx[j] += a * wxr[j * 64];
            gh[j] += c * whr[j * 64];
        }
    }
#pragma unroll
    for (int j = 0; j < 6; ++j) {
        gx[j] += bx[lane + j * 64];
        gh[j] += bh[lane + j * 64];
    }
    // j=0,1 -> i_r/h_r; j=2,3 -> i_i/h_i; j=4,5 -> i_n/h_n
    float rg0 = 1.f / (1.f + __expf(-(gx[0] + gh[0])));
    float rg1 = 1.f / (1.f + __expf(-(gx[1] + gh[1])));
    float ig0 = 1.f / (1.f + __expf(-(gx[2] + gh[2])));
    float ig1 = 1.f / (1.f + __expf(-(gx[3] + gh[3])));
    float ng0 = tanhf(gx[4] + rg0 * gh[4]);
    float ng1 = tanhf(gx[5] + rg1 * gh[5]);
    float hy0 = ng0 + ig0 * (dv0 - ng0);
    float hy1 = ng1 + ig1 * (dv1 - ng1);
    out[(size_t)wave * D + lane] = hy0;
    out[(size_t)wave * D + lane + 64] = hy1;
}

extern "C" void kernel_launch(void* const* d_in, const int* in_sizes, int n_in,
                              void* d_out, int out_size, void* d_ws, size_t ws_size,
                              hipStream_t stream) {
    const float* x      = (const float*)d_in[0];
    const float* hidden = (const float*)d_in[1];
    const int*   adj_src = (const int*)d_in[2];
    const int*   adj_dst = (const int*)d_in[3];
    const float* adj_w   = (const float*)d_in[4];
    const float* gcn_W   = (const float*)d_in[5];
    const float* gcn_b   = (const float*)d_in[6];
    const float* x2h_W   = (const float*)d_in[7];
    const float* x2h_b   = (const float*)d_in[8];
    const float* h2h_W   = (const float*)d_in[9];
    const float* h2h_b   = (const float*)d_in[10];
    float* out = (float*)d_out;

    const int L = 2;
    const int N = in_sizes[0] / D;        // 50000
    const int E = in_sizes[2] / L;        // 800000

    float* A = (float*)d_ws;              // support buffer  [N*D]
    float* B = A + (size_t)N * D;         // agg / h buffer  [N*D]

    const size_t nd = (size_t)N * D;
    dim3 blk(256);
    int gemm_blocks  = (N + 3) / 4;                               // 4 waves/block
    int zero_blocks  = (int)((nd / 4 + 255) / 256);
    int relu_blocks  = zero_blocks;
    int scat_blocks  = (int)(((long long)E * 32 + 255) / 256);

    const float* hcur = x;
    for (int l = 0; l < L; ++l) {
        gemm_rowwave<<<gemm_blocks, blk, 0, stream>>>(hcur, gcn_W + (size_t)l * D * D, A, N);
        zero_f4<<<zero_blocks, blk, 0, stream>>>((float4*)B, (int)(nd / 4));
        scatter_edges<<<scat_blocks, blk, 0, stream>>>(A, adj_src + (size_t)l * E,
                                                       adj_dst + (size_t)l * E,
                                                       adj_w + (size_t)l * E, B, E);
        bias_relu4<<<relu_blocks, blk, 0, stream>>>((float4*)B, gcn_b + (size_t)l * D, (int)(nd / 4));
        hcur = B;
    }
    gru_gate<<<gemm_blocks, blk, 0, stream>>>(B, hidden, x2h_W, x2h_b, h2h_W, h2h_b, out, N);
}

// Round 2
// 1274.707 us; speedup vs baseline: 2.7422x; 2.7422x over previous
//
#include <hip/hip_runtime.h>

#define D 128

// ---------------- support = in @ W  (W is [128][128] row-major) --------------
// One wave (64 lanes) per row; lane l computes output cols l and l+64.
__global__ void gemm_rowwave(const float* __restrict__ in, const float* __restrict__ W,
                             float* __restrict__ out, int nrows) {
    int wave = (blockIdx.x * blockDim.x + threadIdx.x) >> 6;
    int lane = threadIdx.x & 63;
    if (wave >= nrows) return;
    const float* inr = in + (size_t)wave * D;
    float rv0 = inr[lane];
    float rv1 = inr[lane + 64];
    float acc0 = 0.f, acc1 = 0.f;
#pragma unroll 8
    for (int k = 0; k < 64; ++k) {
        float hk = __shfl(rv0, k);
        acc0 += hk * W[k * D + lane];
        acc1 += hk * W[k * D + lane + 64];
    }
#pragma unroll 8
    for (int k = 0; k < 64; ++k) {
        float hk = __shfl(rv1, k);
        acc0 += hk * W[(k + 64) * D + lane];
        acc1 += hk * W[(k + 64) * D + lane + 64];
    }
    out[(size_t)wave * D + lane] = acc0;
    out[(size_t)wave * D + lane + 64] = acc1;
}

// ---------------- zero ints --------------------------------------------------
__global__ void zero_int4(int4* __restrict__ p, int n4) {
    int i = blockIdx.x * blockDim.x + threadIdx.x;
    if (i < n4) p[i] = make_int4(0, 0, 0, 0);
}

// ---------------- CSR build: histogram over dst ------------------------------
__global__ void hist_kernel(const int* __restrict__ dst, int* __restrict__ counts, int E) {
    int i = blockIdx.x * blockDim.x + threadIdx.x;
    if (i < E) atomicAdd(&counts[dst[i]], 1);
}

// ---------------- CSR build: exclusive scan (single block, 1024 thr) ---------
__global__ __launch_bounds__(1024) void scan_kernel(const int* __restrict__ counts,
                                                    int* __restrict__ offsets,
                                                    int* __restrict__ cursor,
                                                    int n, int total) {
    __shared__ int sums[1024];
    int t = threadIdx.x;
    int chunk = (n + 1023) >> 10;
    int lo = t * chunk; if (lo > n) lo = n;
    int hi = lo + chunk; if (hi > n) hi = n;
    int s = 0;
    for (int i = lo; i < hi; ++i) s += counts[i];
    sums[t] = s;
    __syncthreads();
    for (int off = 1; off < 1024; off <<= 1) {
        int x = sums[t];
        int y = (t >= off) ? sums[t - off] : 0;
        __syncthreads();
        sums[t] = x + y;
        __syncthreads();
    }
    int base = (t == 0) ? 0 : sums[t - 1];
    for (int i = lo; i < hi; ++i) {
        int c = counts[i];
        offsets[i] = base;
        cursor[i] = base;
        base += c;
    }
    if (t == 0) offsets[n] = total;
}

// ---------------- CSR build: scatter (src,w) into dst-sorted slots -----------
__global__ void fill_kernel(const int* __restrict__ src, const int* __restrict__ dst,
                            const float* __restrict__ w, int* __restrict__ cursor,
                            int2* __restrict__ srcw, int E) {
    int e = blockIdx.x * blockDim.x + threadIdx.x;
    if (e >= E) return;
    int p = atomicAdd(&cursor[dst[e]], 1);
    srcw[p] = make_int2(src[e], __float_as_int(w[e]));
}

// ---------------- gather: agg[n] = relu(sum_e w*sup[src] + bias) -------------
// One wave per node; lane l owns channels l and l+64. No atomics.
__global__ void gather_nodes(const float* __restrict__ sup, const int2* __restrict__ srcw,
                             const int* __restrict__ offsets, const float* __restrict__ bias,
                             float* __restrict__ out, int N) {
    int node = (blockIdx.x * blockDim.x + threadIdx.x) >> 6;
    int lane = threadIdx.x & 63;
    if (node >= N) return;
    int lo = offsets[node], hi = offsets[node + 1];
    float acc0 = 0.f, acc1 = 0.f;
    for (int j = lo; j < hi; ++j) {
        int2 sw = srcw[j];
        float wt = __int_as_float(sw.y);
        const float* r = sup + (size_t)sw.x * D;
        acc0 += wt * r[lane];
        acc1 += wt * r[lane + 64];
    }
    out[(size_t)node * D + lane] = fmaxf(acc0 + bias[lane], 0.f);
    out[(size_t)node * D + lane + 64] = fmaxf(acc1 + bias[lane + 64], 0.f);
}

// ---------------- fused GRU gates --------------------------------------------
__global__ void gru_gate(const float* __restrict__ h, const float* __restrict__ hidden,
                         const float* __restrict__ Wx, const float* __restrict__ bx,
                         const float* __restrict__ Wh, const float* __restrict__ bh,
                         float* __restrict__ out, int nrows) {
    int wave = (blockIdx.x * blockDim.x + threadIdx.x) >> 6;
    int lane = threadIdx.x & 63;
    if (wave >= nrows) return;
    const float* hr = h + (size_t)wave * D;
    const float* dr = hidden + (size_t)wave * D;
    float hv0 = hr[lane], hv1 = hr[lane + 64];
    float dv0 = dr[lane], dv1 = dr[lane + 64];
    float gx[6] = {0.f, 0.f, 0.f, 0.f, 0.f, 0.f};
    float gh[6] = {0.f, 0.f, 0.f, 0.f, 0.f, 0.f};
#pragma unroll 4
    for (int k = 0; k < 64; ++k) {
        float a = __shfl(hv0, k);
        float c = __shfl(dv0, k);
        const float* wxr = Wx + k * (3 * D) + lane;
        const float* whr = Wh + k * (3 * D) + lane;
#pragma unroll
        for (int j = 0; j < 6; ++j) {
            gx[j] += a * wxr[j * 64];
            gh[j] += c * whr[j * 64];
        }
    }
#pragma unroll 4
    for (int k = 0; k < 64; ++k) {
        float a = __shfl(hv1, k);
        float c = __shfl(dv1, k);
        const float* wxr = Wx + (k + 64) * (3 * D) + lane;
        const float* whr = Wh + (k + 64) * (3 * D) + lane;
#pragma unroll
        for (int j = 0; j < 6; ++j) {
            gx[j] += a * wxr[j * 64];
            gh[j] += c * whr[j * 64];
        }
    }
#pragma unroll
    for (int j = 0; j < 6; ++j) {
        gx[j] += bx[lane + j * 64];
        gh[j] += bh[lane + j * 64];
    }
    float rg0 = 1.f / (1.f + __expf(-(gx[0] + gh[0])));
    float rg1 = 1.f / (1.f + __expf(-(gx[1] + gh[1])));
    float ig0 = 1.f / (1.f + __expf(-(gx[2] + gh[2])));
    float ig1 = 1.f / (1.f + __expf(-(gx[3] + gh[3])));
    float ng0 = tanhf(gx[4] + rg0 * gh[4]);
    float ng1 = tanhf(gx[5] + rg1 * gh[5]);
    float hy0 = ng0 + ig0 * (dv0 - ng0);
    float hy1 = ng1 + ig1 * (dv1 - ng1);
    out[(size_t)wave * D + lane] = hy0;
    out[(size_t)wave * D + lane + 64] = hy1;
}

extern "C" void kernel_launch(void* const* d_in, const int* in_sizes, int n_in,
                              void* d_out, int out_size, void* d_ws, size_t ws_size,
                              hipStream_t stream) {
    const float* x      = (const float*)d_in[0];
    const float* hidden = (const float*)d_in[1];
    const int*   adj_src = (const int*)d_in[2];
    const int*   adj_dst = (const int*)d_in[3];
    const float* adj_w   = (const float*)d_in[4];
    const float* gcn_W   = (const float*)d_in[5];
    const float* gcn_b   = (const float*)d_in[6];
    const float* x2h_W   = (const float*)d_in[7];
    const float* x2h_b   = (const float*)d_in[8];
    const float* h2h_W   = (const float*)d_in[9];
    const float* h2h_b   = (const float*)d_in[10];
    float* out = (float*)d_out;

    const int L = 2;
    const int N = in_sizes[0] / D;        // 50000
    const int E = in_sizes[2] / L;        // 800000
    const size_t nd = (size_t)N * D;

    // workspace layout (all 256B-aligned by construction)
    char* ws = (char*)d_ws;
    float* A       = (float*)ws;                       ws += nd * 4;            // support
    float* B       = (float*)ws;                       ws += nd * 4;            // agg/h
    int*   counts  = (int*)ws;                         ws += ((size_t)N + 64) * 4;
    int*   offsets = (int*)ws;                         ws += ((size_t)N + 64) * 4;
    int*   cursor  = (int*)ws;                         ws += ((size_t)N + 64) * 4;
    int2*  srcw    = (int2*)ws;                        ws += (size_t)E * 8;

    dim3 blk(256);
    int gemm_blocks = (N + 3) / 4;                 // 4 waves/block
    int edge_blocks = (E + 255) / 256;
    int cnt4_blocks = (N / 4 + 255) / 256;

    const float* hcur = x;
    for (int l = 0; l < L; ++l) {
        gemm_rowwave<<<gemm_blocks, blk, 0, stream>>>(hcur, gcn_W + (size_t)l * D * D, A, N);
        zero_int4<<<cnt4_blocks, blk, 0, stream>>>((int4*)counts, N / 4);
        hist_kernel<<<edge_blocks, blk, 0, stream>>>(adj_dst + (size_t)l * E, counts, E);
        scan_kernel<<<1, 1024, 0, stream>>>(counts, offsets, cursor, N, E);
        fill_kernel<<<edge_blocks, blk, 0, stream>>>(adj_src + (size_t)l * E,
                                                     adj_dst + (size_t)l * E,
                                                     adj_w + (size_t)l * E,
                                                     cursor, srcw, E);
        gather_nodes<<<gemm_blocks, blk, 0, stream>>>(A, srcw, offsets,
                                                      gcn_b + (size_t)l * D, B, N);
        hcur = B;
    }
    gru_gate<<<gemm_blocks, blk, 0, stream>>>(B, hidden, x2h_W, x2h_b, h2h_W, h2h_b, out, N);
}

// Round 3
// 876.395 us; speedup vs baseline: 3.9886x; 1.4545x over previous
//
#include <hip/hip_runtime.h>

#define D 128
#define RPW 8            // rows per wave
#define ROWS_PB 32       // rows per block (4 waves * 8)

// ---------------- support = in @ W, 8 rows/wave ------------------------------
// Block stages 32 input rows in LDS; wave w handles rows w*8..w*8+7.
// Lane l owns output cols l and l+64 for each of its 8 rows.
__global__ __launch_bounds__(256) void gemm_rowbatch(const float* __restrict__ in,
                                                     const float* __restrict__ W,
                                                     float* __restrict__ out, int N) {
    __shared__ float sh[ROWS_PB][D];
    int tid = threadIdx.x;
    int row0 = blockIdx.x * ROWS_PB;
    for (int i = tid; i < ROWS_PB * (D / 4); i += 256) {
        int r = i >> 5, c4 = i & 31;
        int row = row0 + r;
        float4 v = (row < N) ? ((const float4*)(in + (size_t)row * D))[c4]
                             : make_float4(0.f, 0.f, 0.f, 0.f);
        ((float4*)sh)[i] = v;
    }
    __syncthreads();
    int wid = tid >> 6, lane = tid & 63;
    int rb = wid * RPW;
    float acc0[RPW], acc1[RPW];
#pragma unroll
    for (int r = 0; r < RPW; ++r) { acc0[r] = 0.f; acc1[r] = 0.f; }
    for (int k = 0; k < D; k += 4) {
        float w0[4], w1[4];
#pragma unroll
        for (int kk = 0; kk < 4; ++kk) {
            w0[kk] = W[(k + kk) * D + lane];
            w1[kk] = W[(k + kk) * D + lane + 64];
        }
#pragma unroll
        for (int r = 0; r < RPW; ++r) {
            float4 a4 = *(const float4*)&sh[rb + r][k];
            acc0[r] = fmaf(a4.x, w0[0], acc0[r]); acc1[r] = fmaf(a4.x, w1[0], acc1[r]);
            acc0[r] = fmaf(a4.y, w0[1], acc0[r]); acc1[r] = fmaf(a4.y, w1[1], acc1[r]);
            acc0[r] = fmaf(a4.z, w0[2], acc0[r]); acc1[r] = fmaf(a4.z, w1[2], acc1[r]);
            acc0[r] = fmaf(a4.w, w0[3], acc0[r]); acc1[r] = fmaf(a4.w, w1[3], acc1[r]);
        }
    }
#pragma unroll
    for (int r = 0; r < RPW; ++r) {
        int row = row0 + rb + r;
        if (row < N) {
            out[(size_t)row * D + lane] = acc0[r];
            out[(size_t)row * D + lane + 64] = acc1[r];
        }
    }
}

// ---------------- zero ints --------------------------------------------------
__global__ void zero_int4(int4* __restrict__ p, int n4) {
    int i = blockIdx.x * blockDim.x + threadIdx.x;
    if (i < n4) p[i] = make_int4(0, 0, 0, 0);
}

// ---------------- CSR build: histogram over dst ------------------------------
__global__ void hist_kernel(const int* __restrict__ dst, int* __restrict__ counts, int E) {
    int i = blockIdx.x * blockDim.x + threadIdx.x;
    if (i < E) atomicAdd(&counts[dst[i]], 1);
}

// ---------------- CSR build: exclusive scan (single block, 1024 thr) ---------
__global__ __launch_bounds__(1024) void scan_kernel(const int* __restrict__ counts,
                                                    int* __restrict__ offsets,
                                                    int* __restrict__ cursor,
                                                    int n, int total) {
    __shared__ int sums[1024];
    int t = threadIdx.x;
    int chunk = (n + 1023) >> 10;
    int lo = t * chunk; if (lo > n) lo = n;
    int hi = lo + chunk; if (hi > n) hi = n;
    int s = 0;
    for (int i = lo; i < hi; ++i) s += counts[i];
    sums[t] = s;
    __syncthreads();
    for (int off = 1; off < 1024; off <<= 1) {
        int x = sums[t];
        int y = (t >= off) ? sums[t - off] : 0;
        __syncthreads();
        sums[t] = x + y;
        __syncthreads();
    }
    int base = (t == 0) ? 0 : sums[t - 1];
    for (int i = lo; i < hi; ++i) {
        int c = counts[i];
        offsets[i] = base;
        cursor[i] = base;
        base += c;
    }
    if (t == 0) offsets[n] = total;
}

// ---------------- CSR build: scatter (src,w) into dst-sorted slots -----------
__global__ void fill_kernel(const int* __restrict__ src, const int* __restrict__ dst,
                            const float* __restrict__ w, int* __restrict__ cursor,
                            int2* __restrict__ srcw, int E) {
    int e = blockIdx.x * blockDim.x + threadIdx.x;
    if (e >= E) return;
    int p = atomicAdd(&cursor[dst[e]], 1);
    srcw[p] = make_int2(src[e], __float_as_int(w[e]));
}

// ---------------- gather: agg[n] = relu(sum_e w*sup[src] + bias) -------------
__global__ void gather_nodes(const float* __restrict__ sup, const int2* __restrict__ srcw,
                             const int* __restrict__ offsets, const float* __restrict__ bias,
                             float* __restrict__ out, int N) {
    int node = (blockIdx.x * blockDim.x + threadIdx.x) >> 6;
    int lane = threadIdx.x & 63;
    if (node >= N) return;
    int lo = offsets[node], hi = offsets[node + 1];
    float acc0 = 0.f, acc1 = 0.f;
    for (int j = lo; j < hi; ++j) {
        int2 sw = srcw[j];
        float wt = __int_as_float(sw.y);
        const float* r = sup + (size_t)sw.x * D;
        acc0 += wt * r[lane];
        acc1 += wt * r[lane + 64];
    }
    out[(size_t)node * D + lane] = fmaxf(acc0 + bias[lane], 0.f);
    out[(size_t)node * D + lane + 64] = fmaxf(acc1 + bias[lane + 64], 0.f);
}

// ---------------- fused GRU gates, 8 rows/wave -------------------------------
// Lane l accumulates gate cols {j*64+l, j=0..5} for 8 rows; weight elements are
// loaded once per wave and reused across the 8 rows.
__global__ __launch_bounds__(256) void gru_gate_b(const float* __restrict__ h,
                                                  const float* __restrict__ hidden,
                                                  const float* __restrict__ Wx,
                                                  const float* __restrict__ bx,
                                                  const float* __restrict__ Wh,
                                                  const float* __restrict__ bh,
                                                  float* __restrict__ out, int N) {
    __shared__ float sh[ROWS_PB][D];
    __shared__ float sd[ROWS_PB][D];
    int tid = threadIdx.x;
    int row0 = blockIdx.x * ROWS_PB;
    for (int i = tid; i < ROWS_PB * (D / 4); i += 256) {
        int r = i >> 5;
        int row = row0 + r;
        int c4 = i & 31;
        float4 v = (row < N) ? ((const float4*)(h + (size_t)row * D))[c4]
                             : make_float4(0.f, 0.f, 0.f, 0.f);
        ((float4*)sh)[i] = v;
        float4 u = (row < N) ? ((const float4*)(hidden + (size_t)row * D))[c4]
                             : make_float4(0.f, 0.f, 0.f, 0.f);
        ((float4*)sd)[i] = u;
    }
    __syncthreads();
    int wid = tid >> 6, lane = tid & 63;
    int rb = wid * RPW;
    float gx[6][RPW], gh[6][RPW];
#pragma unroll
    for (int j = 0; j < 6; ++j)
#pragma unroll
        for (int r = 0; r < RPW; ++r) { gx[j][r] = 0.f; gh[j][r] = 0.f; }

    for (int k = 0; k < D; k += 4) {
        float wxv[6][4], whv[6][4];
#pragma unroll
        for (int kk = 0; kk < 4; ++kk) {
            const float* wxr = Wx + (size_t)(k + kk) * (3 * D) + lane;
            const float* whr = Wh + (size_t)(k + kk) * (3 * D) + lane;
#pragma unroll
            for (int j = 0; j < 6; ++j) {
                wxv[j][kk] = wxr[j * 64];
                whv[j][kk] = whr[j * 64];
            }
        }
#pragma unroll
        for (int r = 0; r < RPW; ++r) {
            float4 a4 = *(const float4*)&sh[rb + r][k];
            float4 c4 = *(const float4*)&sd[rb + r][k];
            float av[4] = {a4.x, a4.y, a4.z, a4.w};
            float cv[4] = {c4.x, c4.y, c4.z, c4.w};
#pragma unroll
            for (int kk = 0; kk < 4; ++kk)
#pragma unroll
                for (int j = 0; j < 6; ++j) {
                    gx[j][r] = fmaf(av[kk], wxv[j][kk], gx[j][r]);
                    gh[j][r] = fmaf(cv[kk], whv[j][kk], gh[j][r]);
                }
        }
    }

    float bx_[6], bh_[6];
#pragma unroll
    for (int j = 0; j < 6; ++j) { bx_[j] = bx[lane + j * 64]; bh_[j] = bh[lane + j * 64]; }

#pragma unroll
    for (int r = 0; r < RPW; ++r) {
        int row = row0 + rb + r;
        if (row >= N) break;
        float xr0 = gx[0][r] + bx_[0], xr1 = gx[1][r] + bx_[1];
        float hr0 = gh[0][r] + bh_[0], hr1 = gh[1][r] + bh_[1];
        float xi0 = gx[2][r] + bx_[2], xi1 = gx[3][r] + bx_[3];
        float hi0 = gh[2][r] + bh_[2], hi1 = gh[3][r] + bh_[3];
        float xn0 = gx[4][r] + bx_[4], xn1 = gx[5][r] + bx_[5];
        float hn0 = gh[4][r] + bh_[4], hn1 = gh[5][r] + bh_[5];
        float rg0 = 1.f / (1.f + __expf(-(xr0 + hr0)));
        float rg1 = 1.f / (1.f + __expf(-(xr1 + hr1)));
        float ig0 = 1.f / (1.f + __expf(-(xi0 + hi0)));
        float ig1 = 1.f / (1.f + __expf(-(xi1 + hi1)));
        float ng0 = tanhf(xn0 + rg0 * hn0);
        float ng1 = tanhf(xn1 + rg1 * hn1);
        float dv0 = sd[rb + r][lane];
        float dv1 = sd[rb + r][lane + 64];
        out[(size_t)row * D + lane] = ng0 + ig0 * (dv0 - ng0);
        out[(size_t)row * D + lane + 64] = ng1 + ig1 * (dv1 - ng1);
    }
}

extern "C" void kernel_launch(void* const* d_in, const int* in_sizes, int n_in,
                              void* d_out, int out_size, void* d_ws, size_t ws_size,
                              hipStream_t stream) {
    const float* x      = (const float*)d_in[0];
    const float* hidden = (const float*)d_in[1];
    const int*   adj_src = (const int*)d_in[2];
    const int*   adj_dst = (const int*)d_in[3];
    const float* adj_w   = (const float*)d_in[4];
    const float* gcn_W   = (const float*)d_in[5];
    const float* gcn_b   = (const float*)d_in[6];
    const float* x2h_W   = (const float*)d_in[7];
    const float* x2h_b   = (const float*)d_in[8];
    const float* h2h_W   = (const float*)d_in[9];
    const float* h2h_b   = (const float*)d_in[10];
    float* out = (float*)d_out;

    const int L = 2;
    const int N = in_sizes[0] / D;        // 50000
    const int E = in_sizes[2] / L;        // 800000
    const size_t nd = (size_t)N * D;

    char* ws = (char*)d_ws;
    float* A       = (float*)ws;                       ws += nd * 4;            // support
    float* B       = (float*)ws;                       ws += nd * 4;            // agg/h
    int*   counts  = (int*)ws;                         ws += ((size_t)N + 64) * 4;
    int*   offsets = (int*)ws;                         ws += ((size_t)N + 64) * 4;
    int*   cursor  = (int*)ws;                         ws += ((size_t)N + 64) * 4;
    int2*  srcw    = (int2*)ws;                        ws += (size_t)E * 8;

    dim3 blk(256);
    int batch_blocks = (N + ROWS_PB - 1) / ROWS_PB;    // 1563
    int gat_blocks   = (N + 3) / 4;                    // 4 waves/block, 1 node/wave
    int edge_blocks  = (E + 255) / 256;
    int cnt4_blocks  = (N / 4 + 255) / 256;

    const float* hcur = x;
    for (int l = 0; l < L; ++l) {
        gemm_rowbatch<<<batch_blocks, blk, 0, stream>>>(hcur, gcn_W + (size_t)l * D * D, A, N);
        zero_int4<<<cnt4_blocks, blk, 0, stream>>>((int4*)counts, N / 4);
        hist_kernel<<<edge_blocks, blk, 0, stream>>>(adj_dst + (size_t)l * E, counts, E);
        scan_kernel<<<1, 1024, 0, stream>>>(counts, offsets, cursor, N, E);
        fill_kernel<<<edge_blocks, blk, 0, stream>>>(adj_src + (size_t)l * E,
                                                     adj_dst + (size_t)l * E,
                                                     adj_w + (size_t)l * E,
                                                     cursor, srcw, E);
        gather_nodes<<<gat_blocks, blk, 0, stream>>>(A, srcw, offsets,
                                                     gcn_b + (size_t)l * D, B, N);
        hcur = B;
    }
    gru_gate_b<<<batch_blocks, blk, 0, stream>>>(B, hidden, x2h_W, x2h_b,
                                                 h2h_W, h2h_b, out, N);
}

// Round 4
// 728.327 us; speedup vs baseline: 4.7994x; 1.2033x over previous
//
#include <hip/hip_runtime.h>

#define D 128
#define RPW 8            // rows per wave (f32 GCN gemm)
#define ROWS_PB 32       // rows per block (4 waves * 8)

typedef __attribute__((ext_vector_type(8))) short short8;
typedef __attribute__((ext_vector_type(4))) float f32x4;

static __device__ __forceinline__ ushort f2bf(float f) {
    unsigned u = __float_as_uint(f);
    unsigned r = (u + 0x7fffu + ((u >> 16) & 1u)) >> 16;   // round-to-nearest-even
    return (ushort)r;
}

// ---------------- support = in @ W, 8 rows/wave (f32) ------------------------
__global__ __launch_bounds__(256) void gemm_rowbatch(const float* __restrict__ in,
                                                     const float* __restrict__ W,
                                                     float* __restrict__ out, int N) {
    __shared__ float sh[ROWS_PB][D];
    int tid = threadIdx.x;
    int row0 = blockIdx.x * ROWS_PB;
    for (int i = tid; i < ROWS_PB * (D / 4); i += 256) {
        int r = i >> 5, c4 = i & 31;
        int row = row0 + r;
        float4 v = (row < N) ? ((const float4*)(in + (size_t)row * D))[c4]
                             : make_float4(0.f, 0.f, 0.f, 0.f);
        ((float4*)sh)[i] = v;
    }
    __syncthreads();
    int wid = tid >> 6, lane = tid & 63;
    int rb = wid * RPW;
    float acc0[RPW], acc1[RPW];
#pragma unroll
    for (int r = 0; r < RPW; ++r) { acc0[r] = 0.f; acc1[r] = 0.f; }
    for (int k = 0; k < D; k += 4) {
        float w0[4], w1[4];
#pragma unroll
        for (int kk = 0; kk < 4; ++kk) {
            w0[kk] = W[(k + kk) * D + lane];
            w1[kk] = W[(k + kk) * D + lane + 64];
        }
#pragma unroll
        for (int r = 0; r < RPW; ++r) {
            float4 a4 = *(const float4*)&sh[rb + r][k];
            acc0[r] = fmaf(a4.x, w0[0], acc0[r]); acc1[r] = fmaf(a4.x, w1[0], acc1[r]);
            acc0[r] = fmaf(a4.y, w0[1], acc0[r]); acc1[r] = fmaf(a4.y, w1[1], acc1[r]);
            acc0[r] = fmaf(a4.z, w0[2], acc0[r]); acc1[r] = fmaf(a4.z, w1[2], acc1[r]);
            acc0[r] = fmaf(a4.w, w0[3], acc0[r]); acc1[r] = fmaf(a4.w, w1[3], acc1[r]);
        }
    }
#pragma unroll
    for (int r = 0; r < RPW; ++r) {
        int row = row0 + rb + r;
        if (row < N) {
            out[(size_t)row * D + lane] = acc0[r];
            out[(size_t)row * D + lane + 64] = acc1[r];
        }
    }
}

// ---------------- zero ints --------------------------------------------------
__global__ void zero_int4(int4* __restrict__ p, int n4) {
    int i = blockIdx.x * blockDim.x + threadIdx.x;
    if (i < n4) p[i] = make_int4(0, 0, 0, 0);
}

// ---------------- CSR build: histogram over dst ------------------------------
__global__ void hist_kernel(const int* __restrict__ dst, int* __restrict__ counts, int E) {
    int i = blockIdx.x * blockDim.x + threadIdx.x;
    if (i < E) atomicAdd(&counts[dst[i]], 1);
}

// ---------------- CSR build: exclusive scan (single block, 1024 thr) ---------
__global__ __launch_bounds__(1024) void scan_kernel(const int* __restrict__ counts,
                                                    int* __restrict__ offsets,
                                                    int* __restrict__ cursor,
                                                    int n, int total) {
    __shared__ int sums[1024];
    int t = threadIdx.x;
    int chunk = (n + 1023) >> 10;
    int lo = t * chunk; if (lo > n) lo = n;
    int hi = lo + chunk; if (hi > n) hi = n;
    int s = 0;
    for (int i = lo; i < hi; ++i) s += counts[i];
    sums[t] = s;
    __syncthreads();
    for (int off = 1; off < 1024; off <<= 1) {
        int x = sums[t];
        int y = (t >= off) ? sums[t - off] : 0;
        __syncthreads();
        sums[t] = x + y;
        __syncthreads();
    }
    int base = (t == 0) ? 0 : sums[t - 1];
    for (int i = lo; i < hi; ++i) {
        int c = counts[i];
        offsets[i] = base;
        cursor[i] = base;
        base += c;
    }
    if (t == 0) offsets[n] = total;
}

// ---------------- CSR build: scatter (src,w) into dst-sorted slots -----------
__global__ void fill_kernel(const int* __restrict__ src, const int* __restrict__ dst,
                            const float* __restrict__ w, int* __restrict__ cursor,
                            int2* __restrict__ srcw, int E) {
    int e = blockIdx.x * blockDim.x + threadIdx.x;
    if (e >= E) return;
    int p = atomicAdd(&cursor[dst[e]], 1);
    srcw[p] = make_int2(src[e], __float_as_int(w[e]));
}

// ---------------- gather: agg[n] = relu(sum_e w*sup[src] + bias) -------------
__global__ void gather_nodes(const float* __restrict__ sup, const int2* __restrict__ srcw,
                             const int* __restrict__ offsets, const float* __restrict__ bias,
                             float* __restrict__ out, int N) {
    int node = (blockIdx.x * blockDim.x + threadIdx.x) >> 6;
    int lane = threadIdx.x & 63;
    if (node >= N) return;
    int lo = offsets[node], hi = offsets[node + 1];
    float acc0 = 0.f, acc1 = 0.f;
    for (int j = lo; j < hi; ++j) {
        int2 sw = srcw[j];
        float wt = __int_as_float(sw.y);
        const float* r = sup + (size_t)sw.x * D;
        acc0 += wt * r[lane];
        acc1 += wt * r[lane + 64];
    }
    out[(size_t)node * D + lane] = fmaxf(acc0 + bias[lane], 0.f);
    out[(size_t)node * D + lane + 64] = fmaxf(acc1 + bias[lane + 64], 0.f);
}

// ---------------- weight transpose + bf16 convert ----------------------------
// wxt[c][k] = bf16(Wx[k][c]),  Wx is [128][384] row-major; wxt is [384][128].
__global__ void convW(const float* __restrict__ Wx, const float* __restrict__ Wh,
                      ushort* __restrict__ wxt, ushort* __restrict__ wht) {
    int i = blockIdx.x * blockDim.x + threadIdx.x;
    if (i >= 384 * 128) return;
    int c = i >> 7, k = i & 127;
    wxt[i] = f2bf(Wx[(size_t)k * 384 + c]);
    wht[i] = f2bf(Wh[(size_t)k * 384 + c]);
}

// ---------------- h / hidden -> bf16 -----------------------------------------
__global__ void convH(const float* __restrict__ h, const float* __restrict__ hid,
                      ushort* __restrict__ hb, ushort* __restrict__ hd, int n4) {
    int i = blockIdx.x * blockDim.x + threadIdx.x;
    if (i >= n4) return;
    float4 a = ((const float4*)h)[i];
    float4 b = ((const float4*)hid)[i];
    ((ushort4*)hb)[i] = make_ushort4(f2bf(a.x), f2bf(a.y), f2bf(a.z), f2bf(a.w));
    ((ushort4*)hd)[i] = make_ushort4(f2bf(b.x), f2bf(b.y), f2bf(b.z), f2bf(b.w));
}

// ---------------- fused GRU via bf16 MFMA ------------------------------------
// Wave handles a 16-row stripe. Per m-pass (m=0..7) computes gate col-tiles
// {m, m+8, m+16} of gx = h@Wx and gh = hidden@Wh via mfma_f32_16x16x32_bf16,
// then applies the gate math for output cols m*16+(lane&15).
// A-frag layout: row = lane&15, k = ks*32 + (lane>>4)*8 + j (8 contiguous bf16).
// B-frag layout: col = lane&15, k same — served by the [384][128] transposed W.
// C/D layout (verified): col = lane&15, row = (lane>>4)*4 + reg.
__global__ __launch_bounds__(256) void gru_mfma(const ushort* __restrict__ hb,
                                                const ushort* __restrict__ hd,
                                                const ushort* __restrict__ wxt,
                                                const ushort* __restrict__ wht,
                                                const float* __restrict__ bx,
                                                const float* __restrict__ bh,
                                                const float* __restrict__ hidden,
                                                float* __restrict__ out, int N) {
    int wid = threadIdx.x >> 6, lane = threadIdx.x & 63;
    int stripe = blockIdx.x * 4 + wid;
    int row0 = stripe * 16;
    if (row0 >= N) return;
    int lr = lane & 15;
    int lk = (lane >> 4) * 8;

    short8 Ah[4], Ad[4];
    const ushort* hrow = hb + (size_t)(row0 + lr) * D + lk;
    const ushort* drow = hd + (size_t)(row0 + lr) * D + lk;
#pragma unroll
    for (int ks = 0; ks < 4; ++ks) {
        Ah[ks] = *(const short8*)(hrow + ks * 32);
        Ad[ks] = *(const short8*)(drow + ks * 32);
    }
    int orow = row0 + (lane >> 4) * 4;

    for (int m = 0; m < 8; ++m) {
        f32x4 ax0{}, ax1{}, ax2{}, ah0{}, ah1{}, ah2{};
        int col = m * 16 + lr;
        const ushort* bxp = wxt + (size_t)col * D + lk;
        const ushort* bhp = wht + (size_t)col * D + lk;
#pragma unroll
        for (int ks = 0; ks < 4; ++ks) {
            short8 w0 = *(const short8*)(bxp + ks * 32);
            short8 w1 = *(const short8*)(bxp + 128 * D + ks * 32);
            short8 w2 = *(const short8*)(bxp + 256 * D + ks * 32);
            short8 v0 = *(const short8*)(bhp + ks * 32);
            short8 v1 = *(const short8*)(bhp + 128 * D + ks * 32);
            short8 v2 = *(const short8*)(bhp + 256 * D + ks * 32);
            ax0 = __builtin_amdgcn_mfma_f32_16x16x32_bf16(Ah[ks], w0, ax0, 0, 0, 0);
            ax1 = __builtin_amdgcn_mfma_f32_16x16x32_bf16(Ah[ks], w1, ax1, 0, 0, 0);
            ax2 = __builtin_amdgcn_mfma_f32_16x16x32_bf16(Ah[ks], w2, ax2, 0, 0, 0);
            ah0 = __builtin_amdgcn_mfma_f32_16x16x32_bf16(Ad[ks], v0, ah0, 0, 0, 0);
            ah1 = __builtin_amdgcn_mfma_f32_16x16x32_bf16(Ad[ks], v1, ah1, 0, 0, 0);
            ah2 = __builtin_amdgcn_mfma_f32_16x16x32_bf16(Ad[ks], v2, ah2, 0, 0, 0);
        }
        float bxr = bx[col], bxi = bx[col + 128], bxn = bx[col + 256];
        float bhr = bh[col], bhi = bh[col + 128], bhn = bh[col + 256];
#pragma unroll
        for (int r = 0; r < 4; ++r) {
            int row = orow + r;
            float ir = ax0[r] + bxr, hr = ah0[r] + bhr;
            float ii = ax1[r] + bxi, hi = ah1[r] + bhi;
            float in_ = ax2[r] + bxn, hn = ah2[r] + bhn;
            float rg = 1.f / (1.f + __expf(-(ir + hr)));
            float ig = 1.f / (1.f + __expf(-(ii + hi)));
            float nx = in_ + rg * hn;
            float ng = 1.f - 2.f / (__expf(2.f * nx) + 1.f);   // tanh(nx)
            float hv = hidden[(size_t)row * D + col];
            out[(size_t)row * D + col] = ng + ig * (hv - ng);
        }
    }
}

extern "C" void kernel_launch(void* const* d_in, const int* in_sizes, int n_in,
                              void* d_out, int out_size, void* d_ws, size_t ws_size,
                              hipStream_t stream) {
    const float* x      = (const float*)d_in[0];
    const float* hidden = (const float*)d_in[1];
    const int*   adj_src = (const int*)d_in[2];
    const int*   adj_dst = (const int*)d_in[3];
    const float* adj_w   = (const float*)d_in[4];
    const float* gcn_W   = (const float*)d_in[5];
    const float* gcn_b   = (const float*)d_in[6];
    const float* x2h_W   = (const float*)d_in[7];
    const float* x2h_b   = (const float*)d_in[8];
    const float* h2h_W   = (const float*)d_in[9];
    const float* h2h_b   = (const float*)d_in[10];
    float* out = (float*)d_out;

    const int L = 2;
    const int N = in_sizes[0] / D;        // 50000
    const int E = in_sizes[2] / L;        // 800000
    const size_t nd = (size_t)N * D;

    char* ws = (char*)d_ws;
    float* A       = (float*)ws;                       ws += nd * 4;            // support / later bf16 bufs
    float* B       = (float*)ws;                       ws += nd * 4;            // agg / h
    int*   counts  = (int*)ws;                         ws += ((size_t)N + 64) * 4;
    int*   offsets = (int*)ws;                         ws += ((size_t)N + 64) * 4;
    int*   cursor  = (int*)ws;                         ws += ((size_t)N + 64) * 4;
    int2*  srcw    = (int2*)ws;                        ws += (size_t)E * 8;
    ushort* wxt    = (ushort*)ws;                      ws += (size_t)384 * 128 * 2;
    ushort* wht    = (ushort*)ws;                      ws += (size_t)384 * 128 * 2;
    // reuse A (freed after last gather) for the bf16 copies of h and hidden
    ushort* hb = (ushort*)A;           // nd ushorts = first half of A
    ushort* hd = (ushort*)A + nd;      // second half of A

    dim3 blk(256);
    int batch_blocks = (N + ROWS_PB - 1) / ROWS_PB;
    int gat_blocks   = (N + 3) / 4;
    int edge_blocks  = (E + 255) / 256;
    int cnt4_blocks  = (N / 4 + 255) / 256;
    int convw_blocks = (384 * 128 + 255) / 256;
    int convh_blocks = (int)((nd / 4 + 255) / 256);
    int stripes      = (N + 15) / 16;
    int gru_blocks   = (stripes + 3) / 4;

    convW<<<convw_blocks, blk, 0, stream>>>(x2h_W, h2h_W, wxt, wht);

    const float* hcur = x;
    for (int l = 0; l < L; ++l) {
        gemm_rowbatch<<<batch_blocks, blk, 0, stream>>>(hcur, gcn_W + (size_t)l * D * D, A, N);
        zero_int4<<<cnt4_blocks, blk, 0, stream>>>((int4*)counts, N / 4);
        hist_kernel<<<edge_blocks, blk, 0, stream>>>(adj_dst + (size_t)l * E, counts, E);
        scan_kernel<<<1, 1024, 0, stream>>>(counts, offsets, cursor, N, E);
        fill_kernel<<<edge_blocks, blk, 0, stream>>>(adj_src + (size_t)l * E,
                                                     adj_dst + (size_t)l * E,
                                                     adj_w + (size_t)l * E,
                                                     cursor, srcw, E);
        gather_nodes<<<gat_blocks, blk, 0, stream>>>(A, srcw, offsets,
                                                     gcn_b + (size_t)l * D, B, N);
        hcur = B;
    }
    convH<<<convh_blocks, blk, 0, stream>>>(B, hidden, hb, hd, (int)(nd / 4));
    gru_mfma<<<gru_blocks, blk, 0, stream>>>(hb, hd, wxt, wht, x2h_b, h2h_b,
                                             hidden, out, N);
}

// Round 5
// 527.726 us; speedup vs baseline: 6.6238x; 1.3801x over previous
//
#include <hip/hip_runtime.h>

#define D 128
#define RPW 8            // rows per wave (f32 GCN gemm)
#define ROWS_PB 32       // rows per block (4 waves * 8)

typedef __attribute__((ext_vector_type(8))) short short8;
typedef __attribute__((ext_vector_type(4))) float f32x4;

static __device__ __forceinline__ ushort f2bf(float f) {
    unsigned u = __float_as_uint(f);
    unsigned r = (u + 0x7fffu + ((u >> 16) & 1u)) >> 16;   // round-to-nearest-even
    return (ushort)r;
}

// ---------------- support = in @ W, 8 rows/wave (f32) ------------------------
__global__ __launch_bounds__(256) void gemm_rowbatch(const float* __restrict__ in,
                                                     const float* __restrict__ W,
                                                     float* __restrict__ out, int N) {
    __shared__ float sh[ROWS_PB][D];
    int tid = threadIdx.x;
    int row0 = blockIdx.x * ROWS_PB;
    for (int i = tid; i < ROWS_PB * (D / 4); i += 256) {
        int r = i >> 5, c4 = i & 31;
        int row = row0 + r;
        float4 v = (row < N) ? ((const float4*)(in + (size_t)row * D))[c4]
                             : make_float4(0.f, 0.f, 0.f, 0.f);
        ((float4*)sh)[i] = v;
    }
    __syncthreads();
    int wid = tid >> 6, lane = tid & 63;
    int rb = wid * RPW;
    float acc0[RPW], acc1[RPW];
#pragma unroll
    for (int r = 0; r < RPW; ++r) { acc0[r] = 0.f; acc1[r] = 0.f; }
    for (int k = 0; k < D; k += 4) {
        float w0[4], w1[4];
#pragma unroll
        for (int kk = 0; kk < 4; ++kk) {
            w0[kk] = W[(k + kk) * D + lane];
            w1[kk] = W[(k + kk) * D + lane + 64];
        }
#pragma unroll
        for (int r = 0; r < RPW; ++r) {
            float4 a4 = *(const float4*)&sh[rb + r][k];
            acc0[r] = fmaf(a4.x, w0[0], acc0[r]); acc1[r] = fmaf(a4.x, w1[0], acc1[r]);
            acc0[r] = fmaf(a4.y, w0[1], acc0[r]); acc1[r] = fmaf(a4.y, w1[1], acc1[r]);
            acc0[r] = fmaf(a4.z, w0[2], acc0[r]); acc1[r] = fmaf(a4.z, w1[2], acc1[r]);
            acc0[r] = fmaf(a4.w, w0[3], acc0[r]); acc1[r] = fmaf(a4.w, w1[3], acc1[r]);
        }
    }
#pragma unroll
    for (int r = 0; r < RPW; ++r) {
        int row = row0 + rb + r;
        if (row < N) {
            out[(size_t)row * D + lane] = acc0[r];
            out[(size_t)row * D + lane + 64] = acc1[r];
        }
    }
}

// ---------------- zero ints --------------------------------------------------
__global__ void zero_int4(int4* __restrict__ p, int n4) {
    int i = blockIdx.x * blockDim.x + threadIdx.x;
    if (i < n4) p[i] = make_int4(0, 0, 0, 0);
}

// ---------------- combined histogram over dst for both layers ----------------
__global__ void hist2_kernel(const int* __restrict__ dst, int* __restrict__ counts,
                             int E2, int E, int N) {
    int i = blockIdx.x * blockDim.x + threadIdx.x;
    if (i >= E2) return;
    int off = (i >= E) ? N : 0;
    atomicAdd(&counts[off + dst[i]], 1);
}

// ---------------- multi-block scan: pass 1 (block partial sums) --------------
// Each block sums 2048 counts (256 thr x 8 via two int4 loads).
__global__ __launch_bounds__(256) void scan_partial(const int4* __restrict__ counts4,
                                                    int* __restrict__ bsum) {
    int b = blockIdx.x, t = threadIdx.x;
    int4 c0 = counts4[(size_t)b * 512 + t * 2];
    int4 c1 = counts4[(size_t)b * 512 + t * 2 + 1];
    int s = c0.x + c0.y + c0.z + c0.w + c1.x + c1.y + c1.z + c1.w;
#pragma unroll
    for (int d = 1; d < 64; d <<= 1) s += __shfl_xor(s, d);
    __shared__ int ws[4];
    if ((t & 63) == 0) ws[t >> 6] = s;
    __syncthreads();
    if (t == 0) bsum[b] = ws[0] + ws[1] + ws[2] + ws[3];
}

// ---------------- multi-block scan: pass 2 (scan of block sums, 1 wave) ------
__global__ void scan_base(const int* __restrict__ bsum, int* __restrict__ bbase, int nb) {
    int lane = threadIdx.x;   // launched with 64 threads
    int run = 0;
    for (int c = 0; c < nb; c += 64) {
        int v = (c + lane < nb) ? bsum[c + lane] : 0;
        int inc = v;
#pragma unroll
        for (int d = 1; d < 64; d <<= 1) {
            int y = __shfl_up(inc, d);
            if (lane >= d) inc += y;
        }
        if (c + lane < nb) bbase[c + lane] = run + inc - v;
        run += __shfl(inc, 63);
    }
}

// ---------------- multi-block scan: pass 3 (apply) ---------------------------
// Writes exclusive prefix into offsets and cursor (identical copies).
__global__ __launch_bounds__(256) void scan_apply(const int4* __restrict__ counts4,
                                                  const int* __restrict__ bbase,
                                                  int4* __restrict__ off4,
                                                  int4* __restrict__ cur4) {
    __shared__ int ts[256];
    int b = blockIdx.x, t = threadIdx.x;
    int4 c0 = counts4[(size_t)b * 512 + t * 2];
    int4 c1 = counts4[(size_t)b * 512 + t * 2 + 1];
    int s = c0.x + c0.y + c0.z + c0.w + c1.x + c1.y + c1.z + c1.w;
    ts[t] = s;
    __syncthreads();
    for (int d = 1; d < 256; d <<= 1) {
        int x = ts[t];
        int y = (t >= d) ? ts[t - d] : 0;
        __syncthreads();
        ts[t] = x + y;
        __syncthreads();
    }
    int base = bbase[b] + ((t == 0) ? 0 : ts[t - 1]);
    int4 o0, o1;
    o0.x = base;
    o0.y = o0.x + c0.x;
    o0.z = o0.y + c0.y;
    o0.w = o0.z + c0.z;
    o1.x = o0.w + c0.w;
    o1.y = o1.x + c1.x;
    o1.z = o1.y + c1.y;
    o1.w = o1.z + c1.z;
    off4[(size_t)b * 512 + t * 2] = o0;
    off4[(size_t)b * 512 + t * 2 + 1] = o1;
    cur4[(size_t)b * 512 + t * 2] = o0;
    cur4[(size_t)b * 512 + t * 2 + 1] = o1;
}

// ---------------- CSR build: scatter (src,w) into dst-sorted slots -----------
__global__ void fill_kernel(const int* __restrict__ src, const int* __restrict__ dst,
                            const float* __restrict__ w, int* __restrict__ cursor,
                            int sub, int2* __restrict__ srcw, int E) {
    int e = blockIdx.x * blockDim.x + threadIdx.x;
    if (e >= E) return;
    int p = atomicAdd(&cursor[dst[e]], 1) - sub;
    srcw[p] = make_int2(src[e], __float_as_int(w[e]));
}

// ---------------- gather: agg[n] = relu(sum_e w*sup[src] + bias) -------------
__global__ void gather_nodes(const float* __restrict__ sup, const int2* __restrict__ srcw,
                             const int* __restrict__ offsets, int sub,
                             const float* __restrict__ bias,
                             float* __restrict__ out, int N) {
    int node = (blockIdx.x * blockDim.x + threadIdx.x) >> 6;
    int lane = threadIdx.x & 63;
    if (node >= N) return;
    int lo = offsets[node] - sub, hi = offsets[node + 1] - sub;
    float acc0 = 0.f, acc1 = 0.f;
    for (int j = lo; j < hi; ++j) {
        int2 sw = srcw[j];
        float wt = __int_as_float(sw.y);
        const float* r = sup + (size_t)sw.x * D;
        acc0 += wt * r[lane];
        acc1 += wt * r[lane + 64];
    }
    out[(size_t)node * D + lane] = fmaxf(acc0 + bias[lane], 0.f);
    out[(size_t)node * D + lane + 64] = fmaxf(acc1 + bias[lane + 64], 0.f);
}

// ---------------- weight transpose + bf16 convert ----------------------------
__global__ void convW(const float* __restrict__ Wx, const float* __restrict__ Wh,
                      ushort* __restrict__ wxt, ushort* __restrict__ wht) {
    int i = blockIdx.x * blockDim.x + threadIdx.x;
    if (i >= 384 * 128) return;
    int c = i >> 7, k = i & 127;
    wxt[i] = f2bf(Wx[(size_t)k * 384 + c]);
    wht[i] = f2bf(Wh[(size_t)k * 384 + c]);
}

// ---------------- h / hidden -> bf16 -----------------------------------------
__global__ void convH(const float* __restrict__ h, const float* __restrict__ hid,
                      ushort* __restrict__ hb, ushort* __restrict__ hd, int n4) {
    int i = blockIdx.x * blockDim.x + threadIdx.x;
    if (i >= n4) return;
    float4 a = ((const float4*)h)[i];
    float4 b = ((const float4*)hid)[i];
    ((ushort4*)hb)[i] = make_ushort4(f2bf(a.x), f2bf(a.y), f2bf(a.z), f2bf(a.w));
    ((ushort4*)hd)[i] = make_ushort4(f2bf(b.x), f2bf(b.y), f2bf(b.z), f2bf(b.w));
}

// ---------------- fused GRU via bf16 MFMA ------------------------------------
__global__ __launch_bounds__(256) void gru_mfma(const ushort* __restrict__ hb,
                                                const ushort* __restrict__ hd,
                                                const ushort* __restrict__ wxt,
                                                const ushort* __restrict__ wht,
                                                const float* __restrict__ bx,
                                                const float* __restrict__ bh,
                                                const float* __restrict__ hidden,
                                                float* __restrict__ out, int N) {
    int wid = threadIdx.x >> 6, lane = threadIdx.x & 63;
    int stripe = blockIdx.x * 4 + wid;
    int row0 = stripe * 16;
    if (row0 >= N) return;
    int lr = lane & 15;
    int lk = (lane >> 4) * 8;

    short8 Ah[4], Ad[4];
    const ushort* hrow = hb + (size_t)(row0 + lr) * D + lk;
    const ushort* drow = hd + (size_t)(row0 + lr) * D + lk;
#pragma unroll
    for (int ks = 0; ks < 4; ++ks) {
        Ah[ks] = *(const short8*)(hrow + ks * 32);
        Ad[ks] = *(const short8*)(drow + ks * 32);
    }
    int orow = row0 + (lane >> 4) * 4;

    for (int m = 0; m < 8; ++m) {
        f32x4 ax0{}, ax1{}, ax2{}, ah0{}, ah1{}, ah2{};
        int col = m * 16 + lr;
        const ushort* bxp = wxt + (size_t)col * D + lk;
        const ushort* bhp = wht + (size_t)col * D + lk;
#pragma unroll
        for (int ks = 0; ks < 4; ++ks) {
            short8 w0 = *(const short8*)(bxp + ks * 32);
            short8 w1 = *(const short8*)(bxp + 128 * D + ks * 32);
            short8 w2 = *(const short8*)(bxp + 256 * D + ks * 32);
            short8 v0 = *(const short8*)(bhp + ks * 32);
            short8 v1 = *(const short8*)(bhp + 128 * D + ks * 32);
            short8 v2 = *(const short8*)(bhp + 256 * D + ks * 32);
            ax0 = __builtin_amdgcn_mfma_f32_16x16x32_bf16(Ah[ks], w0, ax0, 0, 0, 0);
            ax1 = __builtin_amdgcn_mfma_f32_16x16x32_bf16(Ah[ks], w1, ax1, 0, 0, 0);
            ax2 = __builtin_amdgcn_mfma_f32_16x16x32_bf16(Ah[ks], w2, ax2, 0, 0, 0);
            ah0 = __builtin_amdgcn_mfma_f32_16x16x32_bf16(Ad[ks], v0, ah0, 0, 0, 0);
            ah1 = __builtin_amdgcn_mfma_f32_16x16x32_bf16(Ad[ks], v1, ah1, 0, 0, 0);
            ah2 = __builtin_amdgcn_mfma_f32_16x16x32_bf16(Ad[ks], v2, ah2, 0, 0, 0);
        }
        float bxr = bx[col], bxi = bx[col + 128], bxn = bx[col + 256];
        float bhr = bh[col], bhi = bh[col + 128], bhn = bh[col + 256];
#pragma unroll
        for (int r = 0; r < 4; ++r) {
            int row = orow + r;
            float ir = ax0[r] + bxr, hr = ah0[r] + bhr;
            float ii = ax1[r] + bxi, hi = ah1[r] + bhi;
            float in_ = ax2[r] + bxn, hn = ah2[r] + bhn;
            float rg = 1.f / (1.f + __expf(-(ir + hr)));
            float ig = 1.f / (1.f + __expf(-(ii + hi)));
            float nx = in_ + rg * hn;
            float ng = 1.f - 2.f / (__expf(2.f * nx) + 1.f);   // tanh(nx)
            float hv = hidden[(size_t)row * D + col];
            out[(size_t)row * D + col] = ng + ig * (hv - ng);
        }
    }
}

extern "C" void kernel_launch(void* const* d_in, const int* in_sizes, int n_in,
                              void* d_out, int out_size, void* d_ws, size_t ws_size,
                              hipStream_t stream) {
    const float* x      = (const float*)d_in[0];
    const float* hidden = (const float*)d_in[1];
    const int*   adj_src = (const int*)d_in[2];
    const int*   adj_dst = (const int*)d_in[3];
    const float* adj_w   = (const float*)d_in[4];
    const float* gcn_W   = (const float*)d_in[5];
    const float* gcn_b   = (const float*)d_in[6];
    const float* x2h_W   = (const float*)d_in[7];
    const float* x2h_b   = (const float*)d_in[8];
    const float* h2h_W   = (const float*)d_in[9];
    const float* h2h_b   = (const float*)d_in[10];
    float* out = (float*)d_out;

    const int L = 2;
    const int N = in_sizes[0] / D;        // 50000
    const int E = in_sizes[2] / L;        // 800000
    const size_t nd = (size_t)N * D;

    const int twoN   = 2 * N;
    const int NB     = (twoN + 2047) / 2048;      // scan blocks (49)
    const int padded = NB * 2048;

    char* ws = (char*)d_ws;
    float* A        = (float*)ws;                 ws += nd * 4;             // support / bf16 bufs
    float* B        = (float*)ws;                 ws += nd * 4;             // agg / h
    int*   counts2  = (int*)ws;                   ws += (size_t)padded * 4;
    int*   offsets2 = (int*)ws;                   ws += ((size_t)padded + 64) * 4;
    int*   cursor2  = (int*)ws;                   ws += ((size_t)padded + 64) * 4;
    int*   bsum     = (int*)ws;                   ws += ((size_t)NB + 64) * 4;
    int*   bbase    = (int*)ws;                   ws += ((size_t)NB + 64) * 4;
    int2*  srcw     = (int2*)ws;                  ws += (size_t)E * 8;
    ushort* wxt     = (ushort*)ws;                ws += (size_t)384 * 128 * 2;
    ushort* wht     = (ushort*)ws;                ws += (size_t)384 * 128 * 2;
    ushort* hb = (ushort*)A;           // bf16 copy of h     (reuses A)
    ushort* hd = (ushort*)A + nd;      // bf16 copy of hidden

    dim3 blk(256);
    int batch_blocks = (N + ROWS_PB - 1) / ROWS_PB;
    int gat_blocks   = (N + 3) / 4;
    int edge_blocks  = (E + 255) / 256;
    int e2_blocks    = (2 * E + 255) / 256;
    int zero_blocks  = (padded / 4 + 255) / 256;
    int convw_blocks = (384 * 128 + 255) / 256;
    int convh_blocks = (int)((nd / 4 + 255) / 256);
    int gru_blocks   = ((N + 15) / 16 + 3) / 4;

    convW<<<convw_blocks, blk, 0, stream>>>(x2h_W, h2h_W, wxt, wht);

    // combined CSR metadata for both layers (counts/offsets/cursor over 2N)
    zero_int4<<<zero_blocks, blk, 0, stream>>>((int4*)counts2, padded / 4);
    hist2_kernel<<<e2_blocks, blk, 0, stream>>>(adj_dst, counts2, 2 * E, E, N);
    scan_partial<<<NB, blk, 0, stream>>>((const int4*)counts2, bsum);
    scan_base<<<1, 64, 0, stream>>>(bsum, bbase, NB);
    scan_apply<<<NB, blk, 0, stream>>>((const int4*)counts2, bbase,
                                       (int4*)offsets2, (int4*)cursor2);

    const float* hcur = x;
    for (int l = 0; l < L; ++l) {
        gemm_rowbatch<<<batch_blocks, blk, 0, stream>>>(hcur, gcn_W + (size_t)l * D * D, A, N);
        fill_kernel<<<edge_blocks, blk, 0, stream>>>(adj_src + (size_t)l * E,
                                                     adj_dst + (size_t)l * E,
                                                     adj_w + (size_t)l * E,
                                                     cursor2 + (size_t)l * N, l * E,
                                                     srcw, E);
        gather_nodes<<<gat_blocks, blk, 0, stream>>>(A, srcw, offsets2 + (size_t)l * N, l * E,
                                                     gcn_b + (size_t)l * D, B, N);
        hcur = B;
    }
    convH<<<convh_blocks, blk, 0, stream>>>(B, hidden, hb, hd, (int)(nd / 4));
    gru_mfma<<<gru_blocks, blk, 0, stream>>>(hb, hd, wxt, wht, x2h_b, h2h_b,
                                             hidden, out, N);
}

// Round 6
// 480.983 us; speedup vs baseline: 7.2675x; 1.0972x over previous
//
#include <hip/hip_runtime.h>

#define D 128
#define RPW 16           // rows per wave (f32 GCN gemm)
#define ROWS_PB 64       // rows per block (4 waves * 16)

typedef __attribute__((ext_vector_type(8))) short short8;
typedef __attribute__((ext_vector_type(4))) float f32x4;

static __device__ __forceinline__ ushort f2bf(float f) {
    unsigned u = __float_as_uint(f);
    unsigned r = (u + 0x7fffu + ((u >> 16) & 1u)) >> 16;   // round-to-nearest-even
    return (ushort)r;
}

// ---------------- support = in @ W, 16 rows/wave (f32) -----------------------
__global__ __launch_bounds__(256) void gemm_rowbatch(const float* __restrict__ in,
                                                     const float* __restrict__ W,
                                                     float* __restrict__ out, int N) {
    __shared__ float sh[ROWS_PB][D];
    int tid = threadIdx.x;
    int row0 = blockIdx.x * ROWS_PB;
    for (int i = tid; i < ROWS_PB * (D / 4); i += 256) {
        int r = i >> 5, c4 = i & 31;
        int row = row0 + r;
        float4 v = (row < N) ? ((const float4*)(in + (size_t)row * D))[c4]
                             : make_float4(0.f, 0.f, 0.f, 0.f);
        ((float4*)sh)[i] = v;
    }
    __syncthreads();
    int wid = tid >> 6, lane = tid & 63;
    int rb = wid * RPW;
    float acc0[RPW], acc1[RPW];
#pragma unroll
    for (int r = 0; r < RPW; ++r) { acc0[r] = 0.f; acc1[r] = 0.f; }
    for (int k = 0; k < D; k += 4) {
        float w0[4], w1[4];
#pragma unroll
        for (int kk = 0; kk < 4; ++kk) {
            w0[kk] = W[(k + kk) * D + lane];
            w1[kk] = W[(k + kk) * D + lane + 64];
        }
#pragma unroll
        for (int r = 0; r < RPW; ++r) {
            float4 a4 = *(const float4*)&sh[rb + r][k];
            acc0[r] = fmaf(a4.x, w0[0], acc0[r]); acc1[r] = fmaf(a4.x, w1[0], acc1[r]);
            acc0[r] = fmaf(a4.y, w0[1], acc0[r]); acc1[r] = fmaf(a4.y, w1[1], acc1[r]);
            acc0[r] = fmaf(a4.z, w0[2], acc0[r]); acc1[r] = fmaf(a4.z, w1[2], acc1[r]);
            acc0[r] = fmaf(a4.w, w0[3], acc0[r]); acc1[r] = fmaf(a4.w, w1[3], acc1[r]);
        }
    }
#pragma unroll
    for (int r = 0; r < RPW; ++r) {
        int row = row0 + rb + r;
        if (row < N) {
            out[(size_t)row * D + lane] = acc0[r];
            out[(size_t)row * D + lane + 64] = acc1[r];
        }
    }
}

// ---------------- zero ints --------------------------------------------------
__global__ void zero_int4(int4* __restrict__ p, int n4) {
    int i = blockIdx.x * blockDim.x + threadIdx.x;
    if (i < n4) p[i] = make_int4(0, 0, 0, 0);
}

// ---------------- combined histogram over dst for both layers ----------------
__global__ void hist2_kernel(const int* __restrict__ dst, int* __restrict__ counts,
                             int E2, int E, int N) {
    int i = blockIdx.x * blockDim.x + threadIdx.x;
    if (i >= E2) return;
    int off = (i >= E) ? N : 0;
    atomicAdd(&counts[off + dst[i]], 1);
}

// ---------------- multi-block scan: pass 1 (block partial sums) --------------
__global__ __launch_bounds__(256) void scan_partial(const int4* __restrict__ counts4,
                                                    int* __restrict__ bsum) {
    int b = blockIdx.x, t = threadIdx.x;
    int4 c0 = counts4[(size_t)b * 512 + t * 2];
    int4 c1 = counts4[(size_t)b * 512 + t * 2 + 1];
    int s = c0.x + c0.y + c0.z + c0.w + c1.x + c1.y + c1.z + c1.w;
#pragma unroll
    for (int d = 1; d < 64; d <<= 1) s += __shfl_xor(s, d);
    __shared__ int ws[4];
    if ((t & 63) == 0) ws[t >> 6] = s;
    __syncthreads();
    if (t == 0) bsum[b] = ws[0] + ws[1] + ws[2] + ws[3];
}

// ---------------- multi-block scan: pass 2 (scan of block sums, 1 wave) ------
__global__ void scan_base(const int* __restrict__ bsum, int* __restrict__ bbase, int nb) {
    int lane = threadIdx.x;   // launched with 64 threads
    int run = 0;
    for (int c = 0; c < nb; c += 64) {
        int v = (c + lane < nb) ? bsum[c + lane] : 0;
        int inc = v;
#pragma unroll
        for (int d = 1; d < 64; d <<= 1) {
            int y = __shfl_up(inc, d);
            if (lane >= d) inc += y;
        }
        if (c + lane < nb) bbase[c + lane] = run + inc - v;
        run += __shfl(inc, 63);
    }
}

// ---------------- multi-block scan: pass 3 (apply) ---------------------------
__global__ __launch_bounds__(256) void scan_apply(const int4* __restrict__ counts4,
                                                  const int* __restrict__ bbase,
                                                  int4* __restrict__ off4,
                                                  int4* __restrict__ cur4) {
    __shared__ int ts[256];
    int b = blockIdx.x, t = threadIdx.x;
    int4 c0 = counts4[(size_t)b * 512 + t * 2];
    int4 c1 = counts4[(size_t)b * 512 + t * 2 + 1];
    int s = c0.x + c0.y + c0.z + c0.w + c1.x + c1.y + c1.z + c1.w;
    ts[t] = s;
    __syncthreads();
    for (int d = 1; d < 256; d <<= 1) {
        int x = ts[t];
        int y = (t >= d) ? ts[t - d] : 0;
        __syncthreads();
        ts[t] = x + y;
        __syncthreads();
    }
    int base = bbase[b] + ((t == 0) ? 0 : ts[t - 1]);
    int4 o0, o1;
    o0.x = base;
    o0.y = o0.x + c0.x;
    o0.z = o0.y + c0.y;
    o0.w = o0.z + c0.z;
    o1.x = o0.w + c0.w;
    o1.y = o1.x + c1.x;
    o1.z = o1.y + c1.y;
    o1.w = o1.z + c1.z;
    off4[(size_t)b * 512 + t * 2] = o0;
    off4[(size_t)b * 512 + t * 2 + 1] = o1;
    cur4[(size_t)b * 512 + t * 2] = o0;
    cur4[(size_t)b * 512 + t * 2 + 1] = o1;
}

// ---------------- CSR build: scatter (src,w) into dst-sorted slots -----------
__global__ void fill_kernel(const int* __restrict__ src, const int* __restrict__ dst,
                            const float* __restrict__ w, int* __restrict__ cursor,
                            int sub, int2* __restrict__ srcw, int E) {
    int e = blockIdx.x * blockDim.x + threadIdx.x;
    if (e >= E) return;
    int p = atomicAdd(&cursor[dst[e]], 1) - sub;
    srcw[p] = make_int2(src[e], __float_as_int(w[e]));
}

// ---------------- gather: agg[n] = relu(sum_e w*sup[src] + bias) -------------
// One wave per node; lane l owns channels 2l, 2l+1 (float2). 4-edge pipeline.
__global__ void gather_nodes(const float* __restrict__ sup, const int2* __restrict__ srcw,
                             const int* __restrict__ offsets, int sub,
                             const float* __restrict__ bias,
                             float* __restrict__ out, int N) {
    int node = (blockIdx.x * blockDim.x + threadIdx.x) >> 6;
    int lane = threadIdx.x & 63;
    if (node >= N) return;
    int lo = offsets[node] - sub, hi = offsets[node + 1] - sub;
    float ax = 0.f, ay = 0.f;
    int c = lane * 2;
    int j = lo;
    for (; j + 4 <= hi; j += 4) {
        int2 s0 = srcw[j], s1 = srcw[j + 1], s2 = srcw[j + 2], s3 = srcw[j + 3];
        float2 v0 = *(const float2*)(sup + (size_t)s0.x * D + c);
        float2 v1 = *(const float2*)(sup + (size_t)s1.x * D + c);
        float2 v2 = *(const float2*)(sup + (size_t)s2.x * D + c);
        float2 v3 = *(const float2*)(sup + (size_t)s3.x * D + c);
        float w0 = __int_as_float(s0.y), w1 = __int_as_float(s1.y);
        float w2 = __int_as_float(s2.y), w3 = __int_as_float(s3.y);
        ax = fmaf(w0, v0.x, ax); ay = fmaf(w0, v0.y, ay);
        ax = fmaf(w1, v1.x, ax); ay = fmaf(w1, v1.y, ay);
        ax = fmaf(w2, v2.x, ax); ay = fmaf(w2, v2.y, ay);
        ax = fmaf(w3, v3.x, ax); ay = fmaf(w3, v3.y, ay);
    }
    for (; j < hi; ++j) {
        int2 sw = srcw[j];
        float wt = __int_as_float(sw.y);
        float2 v = *(const float2*)(sup + (size_t)sw.x * D + c);
        ax = fmaf(wt, v.x, ax); ay = fmaf(wt, v.y, ay);
    }
    float2 bi = *(const float2*)(bias + c);
    float2 o;
    o.x = fmaxf(ax + bi.x, 0.f);
    o.y = fmaxf(ay + bi.y, 0.f);
    *(float2*)(out + (size_t)node * D + c) = o;
}

// ---------------- weight transpose + bf16 convert ----------------------------
__global__ void convW(const float* __restrict__ Wx, const float* __restrict__ Wh,
                      ushort* __restrict__ wxt, ushort* __restrict__ wht) {
    int i = blockIdx.x * blockDim.x + threadIdx.x;
    if (i >= 384 * 128) return;
    int c = i >> 7, k = i & 127;
    wxt[i] = f2bf(Wx[(size_t)k * 384 + c]);
    wht[i] = f2bf(Wh[(size_t)k * 384 + c]);
}

// ---------------- fused GRU via bf16 MFMA (f32 in, conv in-reg) --------------
// Wave owns a 16-row stripe; per iteration computes TWO m-tiles (m, m+4) so 24
// independent B-loads are in flight before each MFMA cluster.
__device__ __forceinline__ void gru_epi(const f32x4& ax0, const f32x4& ax1, const f32x4& ax2,
                                        const f32x4& ah0, const f32x4& ah1, const f32x4& ah2,
                                        int col, int orow,
                                        const float* __restrict__ bx,
                                        const float* __restrict__ bh,
                                        const float* __restrict__ hidden,
                                        float* __restrict__ out) {
    float bxr = bx[col], bxi = bx[col + 128], bxn = bx[col + 256];
    float bhr = bh[col], bhi = bh[col + 128], bhn = bh[col + 256];
#pragma unroll
    for (int r = 0; r < 4; ++r) {
        int row = orow + r;
        float ir = ax0[r] + bxr, hr = ah0[r] + bhr;
        float ii = ax1[r] + bxi, hi = ah1[r] + bhi;
        float in_ = ax2[r] + bxn, hn = ah2[r] + bhn;
        float rg = 1.f / (1.f + __expf(-(ir + hr)));
        float ig = 1.f / (1.f + __expf(-(ii + hi)));
        float nx = in_ + rg * hn;
        float ng = 1.f - 2.f / (__expf(2.f * nx) + 1.f);   // tanh(nx)
        float hv = hidden[(size_t)row * D + col];
        out[(size_t)row * D + col] = ng + ig * (hv - ng);
    }
}

__global__ __launch_bounds__(256) void gru_mfma(const float* __restrict__ h,
                                                const float* __restrict__ hidden,
                                                const ushort* __restrict__ wxt,
                                                const ushort* __restrict__ wht,
                                                const float* __restrict__ bx,
                                                const float* __restrict__ bh,
                                                float* __restrict__ out, int N) {
    int wid = threadIdx.x >> 6, lane = threadIdx.x & 63;
    int stripe = blockIdx.x * 4 + wid;
    int row0 = stripe * 16;
    if (row0 >= N) return;
    int lr = lane & 15;
    int lk = (lane >> 4) * 8;

    // A-fragments: convert f32 -> bf16 in-register.
    short8 Ah[4], Ad[4];
    const float* hrow = h + (size_t)(row0 + lr) * D + lk;
    const float* drow = hidden + (size_t)(row0 + lr) * D + lk;
#pragma unroll
    for (int ks = 0; ks < 4; ++ks) {
        float4 a0 = *(const float4*)(hrow + ks * 32);
        float4 a1 = *(const float4*)(hrow + ks * 32 + 4);
        float4 c0 = *(const float4*)(drow + ks * 32);
        float4 c1 = *(const float4*)(drow + ks * 32 + 4);
        short8 va, vc;
        va[0] = f2bf(a0.x); va[1] = f2bf(a0.y); va[2] = f2bf(a0.z); va[3] = f2bf(a0.w);
        va[4] = f2bf(a1.x); va[5] = f2bf(a1.y); va[6] = f2bf(a1.z); va[7] = f2bf(a1.w);
        vc[0] = f2bf(c0.x); vc[1] = f2bf(c0.y); vc[2] = f2bf(c0.z); vc[3] = f2bf(c0.w);
        vc[4] = f2bf(c1.x); vc[5] = f2bf(c1.y); vc[6] = f2bf(c1.z); vc[7] = f2bf(c1.w);
        Ah[ks] = va;
        Ad[ks] = vc;
    }
    int orow = row0 + (lane >> 4) * 4;

#pragma unroll
    for (int mm = 0; mm < 4; ++mm) {
        int colA = mm * 16 + lr;
        int colB = (mm + 4) * 16 + lr;
        const ushort* bxA = wxt + (size_t)colA * D + lk;
        const ushort* bhA = wht + (size_t)colA * D + lk;
        const ushort* bxB = wxt + (size_t)colB * D + lk;
        const ushort* bhB = wht + (size_t)colB * D + lk;
        f32x4 axA0{}, axA1{}, axA2{}, ahA0{}, ahA1{}, ahA2{};
        f32x4 axB0{}, axB1{}, axB2{}, ahB0{}, ahB1{}, ahB2{};
#pragma unroll
        for (int ks = 0; ks < 4; ++ks) {
            short8 wA0 = *(const short8*)(bxA + ks * 32);
            short8 wA1 = *(const short8*)(bxA + 128 * D + ks * 32);
            short8 wA2 = *(const short8*)(bxA + 256 * D + ks * 32);
            short8 vA0 = *(const short8*)(bhA + ks * 32);
            short8 vA1 = *(const short8*)(bhA + 128 * D + ks * 32);
            short8 vA2 = *(const short8*)(bhA + 256 * D + ks * 32);
            short8 wB0 = *(const short8*)(bxB + ks * 32);
            short8 wB1 = *(const short8*)(bxB + 128 * D + ks * 32);
            short8 wB2 = *(const short8*)(bxB + 256 * D + ks * 32);
            short8 vB0 = *(const short8*)(bhB + ks * 32);
            short8 vB1 = *(const short8*)(bhB + 128 * D + ks * 32);
            short8 vB2 = *(const short8*)(bhB + 256 * D + ks * 32);
            axA0 = __builtin_amdgcn_mfma_f32_16x16x32_bf16(Ah[ks], wA0, axA0, 0, 0, 0);
            axA1 = __builtin_amdgcn_mfma_f32_16x16x32_bf16(Ah[ks], wA1, axA1, 0, 0, 0);
            axA2 = __builtin_amdgcn_mfma_f32_16x16x32_bf16(Ah[ks], wA2, axA2, 0, 0, 0);
            ahA0 = __builtin_amdgcn_mfma_f32_16x16x32_bf16(Ad[ks], vA0, ahA0, 0, 0, 0);
            ahA1 = __builtin_amdgcn_mfma_f32_16x16x32_bf16(Ad[ks], vA1, ahA1, 0, 0, 0);
            ahA2 = __builtin_amdgcn_mfma_f32_16x16x32_bf16(Ad[ks], vA2, ahA2, 0, 0, 0);
            axB0 = __builtin_amdgcn_mfma_f32_16x16x32_bf16(Ah[ks], wB0, axB0, 0, 0, 0);
            axB1 = __builtin_amdgcn_mfma_f32_16x16x32_bf16(Ah[ks], wB1, axB1, 0, 0, 0);
            axB2 = __builtin_amdgcn_mfma_f32_16x16x32_bf16(Ah[ks], wB2, axB2, 0, 0, 0);
            ahB0 = __builtin_amdgcn_mfma_f32_16x16x32_bf16(Ad[ks], vB0, ahB0, 0, 0, 0);
            ahB1 = __builtin_amdgcn_mfma_f32_16x16x32_bf16(Ad[ks], vB1, ahB1, 0, 0, 0);
            ahB2 = __builtin_amdgcn_mfma_f32_16x16x32_bf16(Ad[ks], vB2, ahB2, 0, 0, 0);
        }
        gru_epi(axA0, axA1, axA2, ahA0, ahA1, ahA2, colA, orow, bx, bh, hidden, out);
        gru_epi(axB0, axB1, axB2, ahB0, ahB1, ahB2, colB, orow, bx, bh, hidden, out);
    }
}

extern "C" void kernel_launch(void* const* d_in, const int* in_sizes, int n_in,
                              void* d_out, int out_size, void* d_ws, size_t ws_size,
                              hipStream_t stream) {
    const float* x      = (const float*)d_in[0];
    const float* hidden = (const float*)d_in[1];
    const int*   adj_src = (const int*)d_in[2];
    const int*   adj_dst = (const int*)d_in[3];
    const float* adj_w   = (const float*)d_in[4];
    const float* gcn_W   = (const float*)d_in[5];
    const float* gcn_b   = (const float*)d_in[6];
    const float* x2h_W   = (const float*)d_in[7];
    const float* x2h_b   = (const float*)d_in[8];
    const float* h2h_W   = (const float*)d_in[9];
    const float* h2h_b   = (const float*)d_in[10];
    float* out = (float*)d_out;

    const int L = 2;
    const int N = in_sizes[0] / D;        // 50000
    const int E = in_sizes[2] / L;        // 800000
    const size_t nd = (size_t)N * D;

    const int twoN   = 2 * N;
    const int NB     = (twoN + 2047) / 2048;      // scan blocks (49)
    const int padded = NB * 2048;

    char* ws = (char*)d_ws;
    float* A        = (float*)ws;                 ws += nd * 4;             // support
    float* B        = (float*)ws;                 ws += nd * 4;             // agg / h
    int*   counts2  = (int*)ws;                   ws += (size_t)padded * 4;
    int*   offsets2 = (int*)ws;                   ws += ((size_t)padded + 64) * 4;
    int*   cursor2  = (int*)ws;                   ws += ((size_t)padded + 64) * 4;
    int*   bsum     = (int*)ws;                   ws += ((size_t)NB + 64) * 4;
    int*   bbase    = (int*)ws;                   ws += ((size_t)NB + 64) * 4;
    int2*  srcw     = (int2*)ws;                  ws += (size_t)E * 8;
    ushort* wxt     = (ushort*)ws;                ws += (size_t)384 * 128 * 2;
    ushort* wht     = (ushort*)ws;                ws += (size_t)384 * 128 * 2;

    dim3 blk(256);
    int batch_blocks = (N + ROWS_PB - 1) / ROWS_PB;
    int gat_blocks   = (N + 3) / 4;
    int edge_blocks  = (E + 255) / 256;
    int e2_blocks    = (2 * E + 255) / 256;
    int zero_blocks  = (padded / 4 + 255) / 256;
    int convw_blocks = (384 * 128 + 255) / 256;
    int gru_blocks   = ((N + 15) / 16 + 3) / 4;

    convW<<<convw_blocks, blk, 0, stream>>>(x2h_W, h2h_W, wxt, wht);

    // combined CSR metadata for both layers (counts/offsets/cursor over 2N)
    zero_int4<<<zero_blocks, blk, 0, stream>>>((int4*)counts2, padded / 4);
    hist2_kernel<<<e2_blocks, blk, 0, stream>>>(adj_dst, counts2, 2 * E, E, N);
    scan_partial<<<NB, blk, 0, stream>>>((const int4*)counts2, bsum);
    scan_base<<<1, 64, 0, stream>>>(bsum, bbase, NB);
    scan_apply<<<NB, blk, 0, stream>>>((const int4*)counts2, bbase,
                                       (int4*)offsets2, (int4*)cursor2);

    const float* hcur = x;
    for (int l = 0; l < L; ++l) {
        gemm_rowbatch<<<batch_blocks, blk, 0, stream>>>(hcur, gcn_W + (size_t)l * D * D, A, N);
        fill_kernel<<<edge_blocks, blk, 0, stream>>>(adj_src + (size_t)l * E,
                                                     adj_dst + (size_t)l * E,
                                                     adj_w + (size_t)l * E,
                                                     cursor2 + (size_t)l * N, l * E,
                                                     srcw, E);
        gather_nodes<<<gat_blocks, blk, 0, stream>>>(A, srcw, offsets2 + (size_t)l * N, l * E,
                                                     gcn_b + (size_t)l * D, B, N);
        hcur = B;
    }
    gru_mfma<<<gru_blocks, blk, 0, stream>>>(B, hidden, wxt, wht, x2h_b, h2h_b, out, N);
}